// Round 5
// baseline (109.261 us; speedup 1.0000x reference)
//
#include <hip/hip_runtime.h>
#include <hip/hip_bf16.h>

typedef short bf16x8 __attribute__((ext_vector_type(8)));
typedef float f32x4 __attribute__((ext_vector_type(4)));

constexpr int Nn = 65536;
constexpr int Kk = 256;
constexpr int Dd = 512;
constexpr int RPB = 64;              // rows per block (8 waves: 4 rowsets x 2 col-halves)
constexpr int BK = 64;               // k per phase
constexpr int NPH = Dd / BK;         // 8 phases
constexpr int SLICE = Kk * BK * 2;   // 32768 B staged B slice (all 256 clusters x 64 k)

static __device__ __forceinline__ unsigned short f2bf(float f) {
  __hip_bfloat16 h = __float2bfloat16(f);
  return *reinterpret_cast<unsigned short*>(&h);
}

static __device__ __forceinline__ bf16x8 pack8(float4 u, float4 v) {
  union { unsigned u32[4]; bf16x8 v8; } r;
  r.u32[0] = ((unsigned)f2bf(u.y) << 16) | f2bf(u.x);
  r.u32[1] = ((unsigned)f2bf(u.w) << 16) | f2bf(u.z);
  r.u32[2] = ((unsigned)f2bf(v.y) << 16) | f2bf(v.x);
  r.u32[3] = ((unsigned)f2bf(v.w) << 16) | f2bf(v.z);
  return r.v8;
}

// Build CB image: per k-slice ks (32KB), XOR-swizzled [cluster][64 bf16] layout so the
// main kernel can stage it with a LINEAR copy and read frags conflict-free.
// Also c2[k] = sum_d C[k][d]^2 in fp32.
__global__ __launch_bounds__(64)
void prep_clusters_kernel(const float* __restrict__ C,
                          unsigned char* __restrict__ CBimg,
                          float* __restrict__ c2) {
  const int c = blockIdx.x;
  const int t = threadIdx.x;
  const int ks = t >> 3;            // 0..7 slice
  const int j0 = (t & 7) * 8;       // bf16 col within slice
  const float* p = C + (size_t)c * Dd + ks * BK + j0;
  float4 a = *reinterpret_cast<const float4*>(p);
  float4 b = *reinterpret_cast<const float4*>(p + 4);
  float s = a.x * a.x + a.y * a.y + a.z * a.z + a.w * a.w
          + b.x * b.x + b.y * b.y + b.z * b.z + b.w * b.w;
  uint4 q;
  q.x = ((unsigned)f2bf(a.y) << 16) | f2bf(a.x);
  q.y = ((unsigned)f2bf(a.w) << 16) | f2bf(a.z);
  q.z = ((unsigned)f2bf(b.y) << 16) | f2bf(b.x);
  q.w = ((unsigned)f2bf(b.w) << 16) | f2bf(b.z);
  const int off = (c * 128 + j0 * 2) ^ ((c & 7) << 4);   // 16B-aligned after XOR
  *reinterpret_cast<uint4*>(CBimg + (size_t)ks * SLICE + off) = q;
  #pragma unroll
  for (int m = 1; m < 64; m <<= 1) s += __shfl_xor(s, m, 64);
  if (t == 0) c2[c] = s;
}

// Fused GEMM + q + row-normalize. 512 threads (8 waves). Wave w: rowset=w>>1, chalf=w&1.
// A: global->reg->bf16 (no LDS). B: one 32KB LDS slice per phase, single-buffered,
// reg-staged with loads issued a full phase early (T14 split). acc[8] = 32 regs.
__global__ __launch_bounds__(512)
void cluster_q_kernel(const float* __restrict__ X,
                      const unsigned char* __restrict__ CBimg,
                      const float* __restrict__ c2g,
                      float* __restrict__ out) {
  __shared__ __align__(16) unsigned char Bl[SLICE];
  __shared__ float x2s[RPB];
  __shared__ float rowp[RPB][2];

  const int tid  = threadIdx.x;
  const int lane = tid & 63;
  const int w    = tid >> 6;
  const int rowset = w >> 1;
  const int chalf  = w & 1;
  const int hi = lane >> 4;   // 0..3
  const int lo = lane & 15;   // 0..15
  const int rb = blockIdx.x * RPB + rowset * 16;
  const float* xrow = X + (size_t)(rb + lo) * Dd;   // this lane's A row

  // LDS read bases for B frags: addr(n,ku) = ((p0 + ku*64) ^ sw) + n*2048
  const int sw = (lo & 7) << 4;
  const int p0 = (chalf * 128 + lo) * 128 + hi * 16;
  const unsigned char* b0 = &Bl[(p0) ^ sw];
  const unsigned char* b1 = &Bl[(p0 + 64) ^ sw];

  f32x4 acc[8];
  #pragma unroll
  for (int n = 0; n < 8; ++n)
    #pragma unroll
    for (int r = 0; r < 4; ++r) acc[n][r] = 0.f;

  float4 a[2][4];   // [phase parity][4 x float4 = 16 floats = this lane's BK slice]
  uint4  sb[4];     // B stage regs (64B/thread)
  float  x2p = 0.f;

  auto loadA = [&](int ks) {
    const float* p = xrow + ks * BK;
    a[ks & 1][0] = *reinterpret_cast<const float4*>(p + hi * 8);
    a[ks & 1][1] = *reinterpret_cast<const float4*>(p + hi * 8 + 4);
    a[ks & 1][2] = *reinterpret_cast<const float4*>(p + 32 + hi * 8);
    a[ks & 1][3] = *reinterpret_cast<const float4*>(p + 32 + hi * 8 + 4);
  };
  auto loadBstage = [&](int ks) {
    const unsigned char* s = CBimg + (size_t)ks * SLICE + tid * 16;
    sb[0] = *reinterpret_cast<const uint4*>(s);
    sb[1] = *reinterpret_cast<const uint4*>(s + 8192);
    sb[2] = *reinterpret_cast<const uint4*>(s + 16384);
    sb[3] = *reinterpret_cast<const uint4*>(s + 24576);
  };
  auto writeBstage = [&]() {
    #pragma unroll
    for (int i = 0; i < 4; ++i)
      *reinterpret_cast<uint4*>(&Bl[i * 8192 + tid * 16]) = sb[i];
  };
  auto compute = [&](int ks) {
    #pragma unroll
    for (int i = 0; i < 4; ++i) {
      float4 f = a[ks & 1][i];
      x2p += f.x * f.x + f.y * f.y + f.z * f.z + f.w * f.w;
    }
    bf16x8 af0 = pack8(a[ks & 1][0], a[ks & 1][1]);   // ku=0: k elems hi*8..+8
    bf16x8 af1 = pack8(a[ks & 1][2], a[ks & 1][3]);   // ku=1: k elems 32+hi*8..+8
    #pragma unroll
    for (int n = 0; n < 8; ++n) {
      bf16x8 bf = *reinterpret_cast<const bf16x8*>(b0 + n * 2048);
      acc[n] = __builtin_amdgcn_mfma_f32_16x16x32_bf16(af0, bf, acc[n], 0, 0, 0);
    }
    #pragma unroll
    for (int n = 0; n < 8; ++n) {
      bf16x8 bf = *reinterpret_cast<const bf16x8*>(b1 + n * 2048);
      acc[n] = __builtin_amdgcn_mfma_f32_16x16x32_bf16(af1, bf, acc[n], 0, 0, 0);
    }
  };

  // Prologue: stage slice 0, start A(0).
  loadA(0);
  loadBstage(0);
  writeBstage();
  __syncthreads();

  #pragma unroll
  for (int ks = 0; ks < NPH; ++ks) {
    if (ks < NPH - 1) {
      loadA(ks + 1);        // global loads issued a full phase before use
      loadBstage(ks + 1);
    }
    compute(ks);            // ~500cy: covers the in-flight load latency
    if (ks < NPH - 1) {
      __syncthreads();      // all waves done reading Bl
      writeBstage();        // publish slice ks+1
      __syncthreads();
    }
  }

  // x2: reduce over hi-groups (k-slices) -> every lane holds x2[row=lo]; fp32-exact.
  {
    float s = x2p;
    s += __shfl_xor(s, 16);
    s += __shfl_xor(s, 32);
    if (chalf == 0 && lane < 16) x2s[rowset * 16 + lane] = s;
  }
  __syncthreads();

  float c2v[8];
  #pragma unroll
  for (int n = 0; n < 8; ++n) c2v[n] = c2g[chalf * 128 + n * 16 + lo];
  float x2v[4];
  #pragma unroll
  for (int r = 0; r < 4; ++r) x2v[r] = x2s[rowset * 16 + hi * 4 + r];

  // q = 1/(1+dist) via v_rcp_f32; accumulate half-row sums.
  float rs[4] = {0.f, 0.f, 0.f, 0.f};
  #pragma unroll
  for (int n = 0; n < 8; ++n)
    #pragma unroll
    for (int r = 0; r < 4; ++r) {
      float dist = fmaxf(x2v[r] + c2v[n] - 2.f * acc[n][r], 0.f);
      float qv = __builtin_amdgcn_rcpf(1.f + dist);
      acc[n][r] = qv;
      rs[r] += qv;
    }

  #pragma unroll
  for (int r = 0; r < 4; ++r) {
    float s = rs[r];
    s += __shfl_xor(s, 1); s += __shfl_xor(s, 2);
    s += __shfl_xor(s, 4); s += __shfl_xor(s, 8);
    rs[r] = s;
  }
  if (lo == 0) {
    #pragma unroll
    for (int r = 0; r < 4; ++r) rowp[rowset * 16 + hi * 4 + r][chalf] = rs[r];
  }
  __syncthreads();

  float rinv[4];
  #pragma unroll
  for (int r = 0; r < 4; ++r) {
    const int row = rowset * 16 + hi * 4 + r;
    rinv[r] = __builtin_amdgcn_rcpf(rowp[row][0] + rowp[row][1]);
  }

  #pragma unroll
  for (int n = 0; n < 8; ++n)
    #pragma unroll
    for (int r = 0; r < 4; ++r)
      out[(size_t)(rb + hi * 4 + r) * Kk + chalf * 128 + n * 16 + lo] = acc[n][r] * rinv[r];
}

extern "C" void kernel_launch(void* const* d_in, const int* in_sizes, int n_in,
                              void* d_out, int out_size, void* d_ws, size_t ws_size,
                              hipStream_t stream) {
  const float* X = reinterpret_cast<const float*>(d_in[0]);
  const float* C = reinterpret_cast<const float*>(d_in[1]);
  unsigned char* CBimg = reinterpret_cast<unsigned char*>(d_ws);          // 256 KB swizzled bf16 image
  float* c2 = reinterpret_cast<float*>(reinterpret_cast<char*>(d_ws) + (size_t)NPH * SLICE);
  prep_clusters_kernel<<<Kk, 64, 0, stream>>>(C, CBimg, c2);
  cluster_q_kernel<<<Nn / RPB, 512, 0, stream>>>(X, CBimg, c2, reinterpret_cast<float*>(d_out));
}

// Round 6
// 108.584 us; speedup vs baseline: 1.0062x; 1.0062x over previous
//
#include <hip/hip_runtime.h>
#include <hip/hip_bf16.h>

typedef short bf16x8 __attribute__((ext_vector_type(8)));
typedef float f32x4 __attribute__((ext_vector_type(4)));

constexpr int Nn = 65536;
constexpr int Kk = 256;
constexpr int Dd = 512;
constexpr int RPB = 64;              // rows per block (8 waves: 4 rowsets x 2 col-halves)
constexpr int BK = 64;               // k per phase
constexpr int NPH = Dd / BK;         // 8 phases
constexpr int SLICE = Kk * BK * 2;   // 32768 B staged B slice (all 256 clusters x 64 k)

static __device__ __forceinline__ unsigned short f2bf(float f) {
  __hip_bfloat16 h = __float2bfloat16(f);
  return *reinterpret_cast<unsigned short*>(&h);
}

static __device__ __forceinline__ bf16x8 pack8(float4 u, float4 v) {
  union { unsigned u32[4]; bf16x8 v8; } r;
  r.u32[0] = ((unsigned)f2bf(u.y) << 16) | f2bf(u.x);
  r.u32[1] = ((unsigned)f2bf(u.w) << 16) | f2bf(u.z);
  r.u32[2] = ((unsigned)f2bf(v.y) << 16) | f2bf(v.x);
  r.u32[3] = ((unsigned)f2bf(v.w) << 16) | f2bf(v.z);
  return r.v8;
}

// LDS-visibility-only barrier: does NOT drain vmcnt, so in-flight global loads
// survive the barrier (the R5 killer was __syncthreads' vmcnt(0) drain each phase).
static __device__ __forceinline__ void rbar() {
  asm volatile("s_waitcnt lgkmcnt(0)" ::: "memory");
  __builtin_amdgcn_s_barrier();
  asm volatile("" ::: "memory");
}

// Build CB image: per k-slice ks (32KB), XOR-swizzled [cluster][64 bf16] layout so the
// main kernel can stage it with a LINEAR copy and read frags conflict-free.
// Also c2[k] = sum_d C[k][d]^2 in fp32.
__global__ __launch_bounds__(64)
void prep_clusters_kernel(const float* __restrict__ C,
                          unsigned char* __restrict__ CBimg,
                          float* __restrict__ c2) {
  const int c = blockIdx.x;
  const int t = threadIdx.x;
  const int ks = t >> 3;            // 0..7 slice
  const int j0 = (t & 7) * 8;       // bf16 col within slice
  const float* p = C + (size_t)c * Dd + ks * BK + j0;
  float4 a = *reinterpret_cast<const float4*>(p);
  float4 b = *reinterpret_cast<const float4*>(p + 4);
  float s = a.x * a.x + a.y * a.y + a.z * a.z + a.w * a.w
          + b.x * b.x + b.y * b.y + b.z * b.z + b.w * b.w;
  uint4 q;
  q.x = ((unsigned)f2bf(a.y) << 16) | f2bf(a.x);
  q.y = ((unsigned)f2bf(a.w) << 16) | f2bf(a.z);
  q.z = ((unsigned)f2bf(b.y) << 16) | f2bf(b.x);
  q.w = ((unsigned)f2bf(b.w) << 16) | f2bf(b.z);
  const int off = (c * 128 + j0 * 2) ^ ((c & 7) << 4);   // 16B-aligned after XOR
  *reinterpret_cast<uint4*>(CBimg + (size_t)ks * SLICE + off) = q;
  #pragma unroll
  for (int m = 1; m < 64; m <<= 1) s += __shfl_xor(s, m, 64);
  if (t == 0) c2[c] = s;
}

// Fused GEMM + q + row-normalize. 512 threads (8 waves). Wave w: rowset=w>>1, chalf=w&1.
// A: global->reg->bf16 (no LDS), 2-phase prefetch depth. B: 2x32KB LDS double-buffer,
// reg-staged; sb loads get a full phase of L2 latency cover before the ds_write.
// Phase order: pack A (free regs) -> ds_write next slice -> issue loads ks+2 -> MFMA -> rbar.
__global__ __launch_bounds__(512)
void cluster_q_kernel(const float* __restrict__ X,
                      const unsigned char* __restrict__ CBimg,
                      const float* __restrict__ c2g,
                      float* __restrict__ out) {
  __shared__ __align__(16) unsigned char Bl[2][SLICE];   // 64 KB double-buffered B
  __shared__ float x2s[RPB];
  __shared__ float rowp[RPB][2];

  const int tid  = threadIdx.x;
  const int lane = tid & 63;
  const int w    = tid >> 6;
  const int rowset = w >> 1;
  const int chalf  = w & 1;
  const int hi = lane >> 4;   // 0..3
  const int lo = lane & 15;   // 0..15
  const int rb = blockIdx.x * RPB + rowset * 16;
  const float* xrow = X + (size_t)(rb + lo) * Dd;   // this lane's A row

  // LDS read offsets for B frags: off(n,ku) = ((p0 + ku*64) ^ sw) + n*2048
  const int sw = (lo & 7) << 4;
  const int p0 = (chalf * 128 + lo) * 128 + hi * 16;
  const int o0 = p0 ^ sw;
  const int o1 = (p0 + 64) ^ sw;

  f32x4 acc[8];
  #pragma unroll
  for (int n = 0; n < 8; ++n)
    #pragma unroll
    for (int r = 0; r < 4; ++r) acc[n][r] = 0.f;

  float4 a[2][4];   // [phase parity][16 floats = this lane's BK slice]
  uint4  sb[4];     // B stage regs (64 B/thread)
  float  x2p = 0.f;

  auto loadA = [&](int ks) {
    const float* p = xrow + ks * BK;
    a[ks & 1][0] = *reinterpret_cast<const float4*>(p + hi * 8);
    a[ks & 1][1] = *reinterpret_cast<const float4*>(p + hi * 8 + 4);
    a[ks & 1][2] = *reinterpret_cast<const float4*>(p + 32 + hi * 8);
    a[ks & 1][3] = *reinterpret_cast<const float4*>(p + 32 + hi * 8 + 4);
  };
  auto loadBstage = [&](int ks) {
    const unsigned char* s = CBimg + (size_t)ks * SLICE + tid * 16;
    sb[0] = *reinterpret_cast<const uint4*>(s);
    sb[1] = *reinterpret_cast<const uint4*>(s + 8192);
    sb[2] = *reinterpret_cast<const uint4*>(s + 16384);
    sb[3] = *reinterpret_cast<const uint4*>(s + 24576);
  };
  auto writeBstage = [&](int buf) {
    #pragma unroll
    for (int i = 0; i < 4; ++i)
      *reinterpret_cast<uint4*>(&Bl[buf][i * 8192 + tid * 16]) = sb[i];
  };

  // ---- Prologue: B(0) staged+written, B(1) in sb, A(0)/A(1) in flight.
  loadBstage(0);            // oldest in-flight: retires first
  loadA(0);
  loadA(1);
  writeBstage(0);           // vmcnt waits only the 4 sb loads; A stays in flight
  loadBstage(1);
  rbar();

  #pragma unroll
  for (int ks = 0; ks < NPH; ++ks) {
    // 1. Pack A frags (consumes a[ks&1], loaded 2 phases ago -> retired) + x2 accumulate.
    #pragma unroll
    for (int i = 0; i < 4; ++i) {
      float4 f = a[ks & 1][i];
      x2p += f.x * f.x + f.y * f.y + f.z * f.z + f.w * f.w;
    }
    bf16x8 af0 = pack8(a[ks & 1][0], a[ks & 1][1]);   // k = hi*8..+8
    bf16x8 af1 = pack8(a[ks & 1][2], a[ks & 1][3]);   // k = 32+hi*8..+8
    // 2. Publish slice ks+1 (sb loaded last phase; vmcnt retires sb only).
    if (ks < NPH - 1) writeBstage((ks + 1) & 1);
    // 3. Issue next loads (2-phase depth for A, 1-phase for B-stage).
    if (ks < NPH - 2) {
      loadBstage(ks + 2);
      loadA(ks + 2);        // into a[ks&1], already consumed by the packs above
    }
    // 4. MFMA on slice ks from Bl[ks&1].
    const unsigned char* base = Bl[ks & 1];
    #pragma unroll
    for (int n = 0; n < 8; ++n) {
      bf16x8 bf = *reinterpret_cast<const bf16x8*>(base + o0 + n * 2048);
      acc[n] = __builtin_amdgcn_mfma_f32_16x16x32_bf16(af0, bf, acc[n], 0, 0, 0);
    }
    #pragma unroll
    for (int n = 0; n < 8; ++n) {
      bf16x8 bf = *reinterpret_cast<const bf16x8*>(base + o1 + n * 2048);
      acc[n] = __builtin_amdgcn_mfma_f32_16x16x32_bf16(af1, bf, acc[n], 0, 0, 0);
    }
    // 5. One LDS-only barrier per phase (vmcnt NOT drained).
    if (ks < NPH - 1) rbar();
  }

  // x2: lanes (hi,lo) hold partial over k-chunks; sum over hi -> full row sum for row lo.
  {
    float s = x2p;
    s += __shfl_xor(s, 16);
    s += __shfl_xor(s, 32);
    if (chalf == 0 && lane < 16) x2s[rowset * 16 + lane] = s;
  }
  __syncthreads();

  float c2v[8];
  #pragma unroll
  for (int n = 0; n < 8; ++n) c2v[n] = c2g[chalf * 128 + n * 16 + lo];
  float x2v[4];
  #pragma unroll
  for (int r = 0; r < 4; ++r) x2v[r] = x2s[rowset * 16 + hi * 4 + r];

  // q = 1/(1+dist) via v_rcp_f32 (~1ulp; q<=1 so abs err ~1e-7 << 1e-4 threshold).
  float rs[4] = {0.f, 0.f, 0.f, 0.f};
  #pragma unroll
  for (int n = 0; n < 8; ++n)
    #pragma unroll
    for (int r = 0; r < 4; ++r) {
      float dist = fmaxf(x2v[r] + c2v[n] - 2.f * acc[n][r], 0.f);
      float qv = __builtin_amdgcn_rcpf(1.f + dist);
      acc[n][r] = qv;
      rs[r] += qv;
    }

  #pragma unroll
  for (int r = 0; r < 4; ++r) {
    float s = rs[r];
    s += __shfl_xor(s, 1); s += __shfl_xor(s, 2);
    s += __shfl_xor(s, 4); s += __shfl_xor(s, 8);
    rs[r] = s;
  }
  if (lo == 0) {
    #pragma unroll
    for (int r = 0; r < 4; ++r) rowp[rowset * 16 + hi * 4 + r][chalf] = rs[r];
  }
  __syncthreads();

  float rinv[4];
  #pragma unroll
  for (int r = 0; r < 4; ++r) {
    const int row = rowset * 16 + hi * 4 + r;
    rinv[r] = __builtin_amdgcn_rcpf(rowp[row][0] + rowp[row][1]);
  }

  #pragma unroll
  for (int n = 0; n < 8; ++n)
    #pragma unroll
    for (int r = 0; r < 4; ++r)
      out[(size_t)(rb + hi * 4 + r) * Kk + chalf * 128 + n * 16 + lo] = acc[n][r] * rinv[r];
}

extern "C" void kernel_launch(void* const* d_in, const int* in_sizes, int n_in,
                              void* d_out, int out_size, void* d_ws, size_t ws_size,
                              hipStream_t stream) {
  const float* X = reinterpret_cast<const float*>(d_in[0]);
  const float* C = reinterpret_cast<const float*>(d_in[1]);
  unsigned char* CBimg = reinterpret_cast<unsigned char*>(d_ws);          // 256 KB swizzled bf16 image
  float* c2 = reinterpret_cast<float*>(reinterpret_cast<char*>(d_ws) + (size_t)NPH * SLICE);
  prep_clusters_kernel<<<Kk, 64, 0, stream>>>(C, CBimg, c2);
  cluster_q_kernel<<<Nn / RPB, 512, 0, stream>>>(X, CBimg, c2, reinterpret_cast<float*>(d_out));
}